// Round 3
// baseline (68.183 us; speedup 1.0000x reference)
//
#include <hip/hip_runtime.h>
#include <hip/hip_bf16.h>

#define LOG2E_F 1.4426950408889634f

typedef __attribute__((ext_vector_type(8))) short short8;
typedef __attribute__((ext_vector_type(4))) float f32x4;

__device__ inline unsigned short f2b(float f) {
    __hip_bfloat16 h = __float2bfloat16(f);   // RNE
    return *reinterpret_cast<unsigned short*>(&h);
}

// load 8 consecutive fp32 and convert to one bf16 MFMA fragment (short8)
__device__ inline short8 load_frag_f32(const float* p) {
    const float4 lo = *(const float4*)p;
    const float4 hi = *(const float4*)(p + 4);
    short8 r;
    r[0] = (short)f2b(lo.x); r[1] = (short)f2b(lo.y);
    r[2] = (short)f2b(lo.z); r[3] = (short)f2b(lo.w);
    r[4] = (short)f2b(hi.x); r[5] = (short)f2b(hi.y);
    r[6] = (short)f2b(hi.z); r[7] = (short)f2b(hi.w);
    return r;
}

// =====================================================================
// Kernel 1: QKV in-projection via bf16 MFMA, fp32 output.
// grid (64, 24); same-row blocks share an XCD (flat%8=bx%8) -> L2-served
// A re-reads. Unchanged from round 2 (est ~6us).
// =====================================================================
__global__ __launch_bounds__(256) void qkv_mfma_kernel(
    const float* __restrict__ x, const float* __restrict__ W,
    const float* __restrict__ bias,
    float* __restrict__ qb, float* __restrict__ kb, float* __restrict__ vb)
{
    const int lane = threadIdx.x & 63;
    const int wv   = threadIdx.x >> 6;
    const int r16  = lane & 15;
    const int kg   = lane >> 4;
    const int ct   = blockIdx.y;
    const int col  = ct * 16 + r16;    // 0..383

    short8 bfr[4];
    #pragma unroll
    for (int ks = 0; ks < 4; ++ks)
        bfr[ks] = load_frag_f32(W + (size_t)col * 128 + ks * 32 + kg * 8);

    const float bias_v = bias[col];
    float scale = 1.0f;
    float* dst; int dcol = col;
    if (col < 128)      { dst = qb; scale = 0.25f; }   // q / sqrt(dh)
    else if (col < 256) { dst = kb; dcol = col - 128; }
    else                { dst = vb; dcol = col - 256; }

    #pragma unroll
    for (int i = 0; i < 4; ++i) {
        const int rt = (blockIdx.x * 4 + wv) + i * 256;   // 0..1023
        const float* arow = x + (size_t)(rt * 16 + r16) * 128 + kg * 8;
        f32x4 acc = {0.f, 0.f, 0.f, 0.f};
        #pragma unroll
        for (int ks = 0; ks < 4; ++ks) {
            const short8 af = load_frag_f32(arow + ks * 32);
            acc = __builtin_amdgcn_mfma_f32_16x16x32_bf16(af, bfr[ks], acc, 0, 0, 0);
        }
        // C/D: col = lane&15, row = (lane>>4)*4 + reg   [m89-verified]
        #pragma unroll
        for (int r = 0; r < 4; ++r) {
            const int row = rt * 16 + kg * 4 + r;
            dst[(size_t)row * 128 + dcol] = (acc[r] + bias_v) * scale;
        }
    }
}

// =====================================================================
// Kernel 2: fused lattice attention, SINGLE-PASS online softmax.
// One block per system; thread = (qi, h). Running (m, den, acc) with
// defer-rescale THR=8 (log2 domain); no s2[32] array, no v_log_f32,
// no second V pass. p = exp2(b - m) * ssum, b = log2e*dot + al2*min(d2).
// =====================================================================
__global__ __launch_bounds__(256) void attn_kernel(
    const float* __restrict__ qb, const float* __restrict__ kb,
    const float* __restrict__ vb, const float* __restrict__ alpha,
    const float* __restrict__ dist2, unsigned short* __restrict__ aggb)
{
    __shared__ float kl[32][160];   // [kj][h*20 + d] (20-pad: b128 conflict-free)
    __shared__ float vl[32][160];
    const int sys = blockIdx.x;
    const int tid = threadIdx.x;
    const int qi  = tid >> 3;
    const int h   = tid & 7;
    const int base = sys << 5;

    #pragma unroll
    for (int it = 0; it < 4; ++it) {
        const int f  = tid + (it << 8);
        const int kj = f >> 5;
        const int c  = (f & 31) << 2;
        const int l  = ((c >> 4) * 20) + (c & 15);
        *(float4*)(&kl[kj][l]) = *(const float4*)(kb + (size_t)(base + kj) * 128 + c);
        *(float4*)(&vl[kj][l]) = *(const float4*)(vb + (size_t)(base + kj) * 128 + c);
    }

    float qreg[16];
    {
        const float* qrow = qb + (size_t)(base + qi) * 128 + h * 16;
        #pragma unroll
        for (int d4 = 0; d4 < 4; ++d4) {
            const float4 t = *(const float4*)(qrow + (d4 << 2));
            qreg[d4 * 4 + 0] = t.x; qreg[d4 * 4 + 1] = t.y;
            qreg[d4 * 4 + 2] = t.z; qreg[d4 * 4 + 3] = t.w;
        }
    }
    const float al2 = alpha[(size_t)(base + qi) * 8 + h] * LOG2E_F; // < 0

    __syncthreads();

    float m = -1e30f;
    float den = 0.f;
    float acc[16] = {};
    const float* dp = dist2 + (size_t)(sys * 1024 + qi * 32) * 16;

    #pragma unroll 4
    for (int kj = 0; kj < 32; ++kj, dp += 16) {
        // ---- lattice term: ssum = sum_r exp2(al2*(d2 - mn)), c0 = al2*mn ----
        const float4 t0 = *(const float4*)(dp + 0);
        const float4 t1 = *(const float4*)(dp + 4);
        const float4 t2 = *(const float4*)(dp + 8);
        const float4 t3 = *(const float4*)(dp + 12);
        const float mn = fminf(
            fminf(fminf(fminf(t0.x, t0.y), fminf(t0.z, t0.w)),
                  fminf(fminf(t1.x, t1.y), fminf(t1.z, t1.w))),
            fminf(fminf(fminf(t2.x, t2.y), fminf(t2.z, t2.w)),
                  fminf(fminf(t3.x, t3.y), fminf(t3.z, t3.w))));
        const float c0 = al2 * mn;   // = max_r(al2*d2), al2<0
        float e0 = __builtin_amdgcn_exp2f(fmaf(al2, t0.x, -c0));
        e0 += __builtin_amdgcn_exp2f(fmaf(al2, t0.y, -c0));
        e0 += __builtin_amdgcn_exp2f(fmaf(al2, t0.z, -c0));
        e0 += __builtin_amdgcn_exp2f(fmaf(al2, t0.w, -c0));
        float e1 = __builtin_amdgcn_exp2f(fmaf(al2, t1.x, -c0));
        e1 += __builtin_amdgcn_exp2f(fmaf(al2, t1.y, -c0));
        e1 += __builtin_amdgcn_exp2f(fmaf(al2, t1.z, -c0));
        e1 += __builtin_amdgcn_exp2f(fmaf(al2, t1.w, -c0));
        float e2 = __builtin_amdgcn_exp2f(fmaf(al2, t2.x, -c0));
        e2 += __builtin_amdgcn_exp2f(fmaf(al2, t2.y, -c0));
        e2 += __builtin_amdgcn_exp2f(fmaf(al2, t2.z, -c0));
        e2 += __builtin_amdgcn_exp2f(fmaf(al2, t2.w, -c0));
        float e3 = __builtin_amdgcn_exp2f(fmaf(al2, t3.x, -c0));
        e3 += __builtin_amdgcn_exp2f(fmaf(al2, t3.y, -c0));
        e3 += __builtin_amdgcn_exp2f(fmaf(al2, t3.z, -c0));
        e3 += __builtin_amdgcn_exp2f(fmaf(al2, t3.w, -c0));
        const float ssum = (e0 + e1) + (e2 + e3);   // in [1, 16]

        // ---- q.k dot from LDS ----
        const float* kr = &kl[kj][h * 20];
        const float4 k0 = *(const float4*)(kr + 0);
        const float4 k1 = *(const float4*)(kr + 4);
        const float4 k2 = *(const float4*)(kr + 8);
        const float4 k3 = *(const float4*)(kr + 12);
        float p0 = qreg[0] * k0.x, p1 = qreg[1] * k0.y;
        float p2 = qreg[2] * k0.z, p3 = qreg[3] * k0.w;
        p0 = fmaf(qreg[4],  k1.x, p0); p1 = fmaf(qreg[5],  k1.y, p1);
        p2 = fmaf(qreg[6],  k1.z, p2); p3 = fmaf(qreg[7],  k1.w, p3);
        p0 = fmaf(qreg[8],  k2.x, p0); p1 = fmaf(qreg[9],  k2.y, p1);
        p2 = fmaf(qreg[10], k2.z, p2); p3 = fmaf(qreg[11], k2.w, p3);
        p0 = fmaf(qreg[12], k3.x, p0); p1 = fmaf(qreg[13], k3.y, p1);
        p2 = fmaf(qreg[14], k3.z, p2); p3 = fmaf(qreg[15], k3.w, p3);
        const float dot = (p0 + p1) + (p2 + p3);

        // b = log2-domain score minus the (bounded) log2(ssum) term
        const float b = fmaf(dot, LOG2E_F, c0);

        // ---- deferred-max online rescale (THR = 8 in log2 domain) ----
        if (b - m > 8.0f) {
            const float sc = __builtin_amdgcn_exp2f(m - b);  // 0 on first hit
            den *= sc;
            #pragma unroll
            for (int d = 0; d < 16; ++d) acc[d] *= sc;
            m = b;
        }
        const float p = __builtin_amdgcn_exp2f(b - m) * ssum;  // p <= 2^8 * 16
        den += p;

        // ---- PV accumulate ----
        const float* vr = &vl[kj][h * 20];
        const float4 v0 = *(const float4*)(vr + 0);
        const float4 v1 = *(const float4*)(vr + 4);
        const float4 v2 = *(const float4*)(vr + 8);
        const float4 v3 = *(const float4*)(vr + 12);
        acc[0]  = fmaf(p, v0.x, acc[0]);  acc[1]  = fmaf(p, v0.y, acc[1]);
        acc[2]  = fmaf(p, v0.z, acc[2]);  acc[3]  = fmaf(p, v0.w, acc[3]);
        acc[4]  = fmaf(p, v1.x, acc[4]);  acc[5]  = fmaf(p, v1.y, acc[5]);
        acc[6]  = fmaf(p, v1.z, acc[6]);  acc[7]  = fmaf(p, v1.w, acc[7]);
        acc[8]  = fmaf(p, v2.x, acc[8]);  acc[9]  = fmaf(p, v2.y, acc[9]);
        acc[10] = fmaf(p, v2.z, acc[10]); acc[11] = fmaf(p, v2.w, acc[11]);
        acc[12] = fmaf(p, v3.x, acc[12]); acc[13] = fmaf(p, v3.y, acc[13]);
        acc[14] = fmaf(p, v3.z, acc[14]); acc[15] = fmaf(p, v3.w, acc[15]);
    }

    const float inv = 1.0f / den;
    unsigned short* op = aggb + (size_t)(base + qi) * 128 + h * 16;
    uint4 o0, o1;
    o0.x = (unsigned)f2b(acc[0]  * inv) | ((unsigned)f2b(acc[1]  * inv) << 16);
    o0.y = (unsigned)f2b(acc[2]  * inv) | ((unsigned)f2b(acc[3]  * inv) << 16);
    o0.z = (unsigned)f2b(acc[4]  * inv) | ((unsigned)f2b(acc[5]  * inv) << 16);
    o0.w = (unsigned)f2b(acc[6]  * inv) | ((unsigned)f2b(acc[7]  * inv) << 16);
    o1.x = (unsigned)f2b(acc[8]  * inv) | ((unsigned)f2b(acc[9]  * inv) << 16);
    o1.y = (unsigned)f2b(acc[10] * inv) | ((unsigned)f2b(acc[11] * inv) << 16);
    o1.z = (unsigned)f2b(acc[12] * inv) | ((unsigned)f2b(acc[13] * inv) << 16);
    o1.w = (unsigned)f2b(acc[14] * inv) | ((unsigned)f2b(acc[15] * inv) << 16);
    *(uint4*)op       = o0;
    *(uint4*)(op + 8) = o1;
}

// =====================================================================
// Kernel 3: out-projection via bf16 MFMA. Unchanged from round 2.
// =====================================================================
__global__ __launch_bounds__(256) void out_mfma_kernel(
    const unsigned short* __restrict__ aggb, const float* __restrict__ W,
    const float* __restrict__ bias, float* __restrict__ out)
{
    const int lane = threadIdx.x & 63;
    const int wv   = threadIdx.x >> 6;
    const int r16  = lane & 15;
    const int kg   = lane >> 4;
    const int ct   = blockIdx.y;
    const int col  = ct * 16 + r16;    // 0..127

    short8 bfr[4];
    #pragma unroll
    for (int ks = 0; ks < 4; ++ks)
        bfr[ks] = load_frag_f32(W + (size_t)col * 128 + ks * 32 + kg * 8);

    const float bias_v = bias[col];

    #pragma unroll
    for (int i = 0; i < 2; ++i) {
        const int rt = (blockIdx.x * 4 + wv) + i * 512;   // 0..1023
        const unsigned short* arow = aggb + (size_t)(rt * 16 + r16) * 128 + kg * 8;
        f32x4 acc = {0.f, 0.f, 0.f, 0.f};
        #pragma unroll
        for (int ks = 0; ks < 4; ++ks) {
            const short8 af = *(const short8*)(arow + ks * 32);
            acc = __builtin_amdgcn_mfma_f32_16x16x32_bf16(af, bfr[ks], acc, 0, 0, 0);
        }
        #pragma unroll
        for (int r = 0; r < 4; ++r) {
            const int row = rt * 16 + kg * 4 + r;
            out[(size_t)row * 128 + col] = acc[r] + bias_v;
        }
    }
}

// =====================================================================
extern "C" void kernel_launch(void* const* d_in, const int* in_sizes, int n_in,
                              void* d_out, int out_size, void* d_ws, size_t ws_size,
                              hipStream_t stream)
{
    const float* x     = (const float*)d_in[0];   // [16384,128]
    const float* Win   = (const float*)d_in[1];   // [384,128]
    const float* bin   = (const float*)d_in[2];   // [384]
    const float* Wout  = (const float*)d_in[3];   // [128,128]
    const float* bout  = (const float*)d_in[4];   // [128]
    const float* alpha = (const float*)d_in[5];   // [16384,8]
    const float* dist2 = (const float*)d_in[6];   // [524288,16]
    // d_in[7] edges, d_in[8] batch: dense block structure, derived analytically

    float* qb = (float*)d_ws;                     // [16384,128] f32, pre-scaled
    float* kb = qb + (size_t)16384 * 128;
    float* vb = kb + (size_t)16384 * 128;
    unsigned short* aggb = (unsigned short*)(vb + (size_t)16384 * 128); // bf16
    float* out = (float*)d_out;

    qkv_mfma_kernel<<<dim3(64, 24), 256, 0, stream>>>(x, Win, bin, qb, kb, vb);
    attn_kernel<<<dim3(512), 256, 0, stream>>>(qb, kb, vb, alpha, dist2, aggb);
    out_mfma_kernel<<<dim3(128, 8), 256, 0, stream>>>(aggb, Wout, bout, out);
}

// Round 4
// 43.529 us; speedup vs baseline: 1.5664x; 1.5664x over previous
//
#include <hip/hip_runtime.h>
#include <hip/hip_bf16.h>

#define LOG2E_F 1.4426950408889634f

typedef __attribute__((ext_vector_type(8))) short short8;
typedef __attribute__((ext_vector_type(4))) float f32x4;

__device__ inline unsigned short f2b(float f) {
    __hip_bfloat16 h = __float2bfloat16(f);   // RNE
    return *reinterpret_cast<unsigned short*>(&h);
}

// load 8 consecutive fp32 and convert to one bf16 MFMA fragment (short8)
__device__ inline short8 load_frag_f32(const float* p) {
    const float4 lo = *(const float4*)p;
    const float4 hi = *(const float4*)(p + 4);
    short8 r;
    r[0] = (short)f2b(lo.x); r[1] = (short)f2b(lo.y);
    r[2] = (short)f2b(lo.z); r[3] = (short)f2b(lo.w);
    r[4] = (short)f2b(hi.x); r[5] = (short)f2b(hi.y);
    r[6] = (short)f2b(hi.z); r[7] = (short)f2b(hi.w);
    return r;
}

// =====================================================================
// Fully fused Crystalformer layer: one block per system (512 blocks,
// 256 threads, 4 waves). No global intermediates at all.
//   Phase 1: QKV bf16-MFMA -> LDS qkvl[3][32][164] (fp32)
//   Phase 2: online-softmax lattice attention -> LDS aggb[32][136] (bf16)
//   Phase 3: out-projection bf16-MFMA -> d_out
// LDS stride 164 floats: attn b128 reads hit all 32 banks once per
// 8-lane h-group; phase-1 scalar writes are <=2-way.
// =====================================================================
__global__ __launch_bounds__(256) void fused_attn_kernel(
    const float* __restrict__ x, const float* __restrict__ Win,
    const float* __restrict__ bin, const float* __restrict__ Wout,
    const float* __restrict__ bout, const float* __restrict__ alpha,
    const float* __restrict__ dist2, float* __restrict__ out)
{
    __shared__ float qkvl[3][32][164];          // 63.0 KB
    __shared__ unsigned short aggb[32][136];    //  8.7 KB

    const int sys  = blockIdx.x;
    const int tid  = threadIdx.x;
    const int lane = tid & 63;
    const int wv   = tid >> 6;
    const int r16  = lane & 15;
    const int kg   = lane >> 4;
    const int base = sys << 5;

    // ---------------- Phase 1: QKV projection into LDS ----------------
    // A-frags: x rows of this system's two 16-atom row-tiles.
    short8 af[2][4];
    #pragma unroll
    for (int rt = 0; rt < 2; ++rt)
        #pragma unroll
        for (int ks = 0; ks < 4; ++ks)
            af[rt][ks] = load_frag_f32(
                x + (size_t)(base + rt * 16 + r16) * 128 + ks * 32 + kg * 8);

    // wave wv owns col-tiles [6wv, 6wv+6) of 24 (384 cols).
    #pragma unroll
    for (int j = 0; j < 6; ++j) {
        const int ct = wv * 6 + j;            // 0..23 (wave-uniform)
        const int c  = ct * 16 + r16;         // global col 0..383
        short8 bf[4];
        #pragma unroll
        for (int ks = 0; ks < 4; ++ks)
            bf[ks] = load_frag_f32(Win + (size_t)c * 128 + ks * 32 + kg * 8);
        const float bias_v = bin[c];
        const int   bufi   = ct >> 3;         // 0=q, 1=k, 2=v
        const int   h      = ct & 7;
        const float scale  = (bufi == 0) ? 0.25f : 1.0f;   // q / sqrt(dh)

        #pragma unroll
        for (int rt = 0; rt < 2; ++rt) {
            f32x4 acc = {0.f, 0.f, 0.f, 0.f};
            #pragma unroll
            for (int ks = 0; ks < 4; ++ks)
                acc = __builtin_amdgcn_mfma_f32_16x16x32_bf16(af[rt][ks], bf[ks], acc, 0, 0, 0);
            // C/D: col = lane&15 (=r16 -> feature), row = kg*4+r (-> atom)
            #pragma unroll
            for (int r = 0; r < 4; ++r) {
                const int atom = rt * 16 + kg * 4 + r;
                qkvl[bufi][atom][h * 20 + r16] = (acc[r] + bias_v) * scale;
            }
        }
    }

    // alpha load (global, independent of LDS) before the barrier
    const int qi = tid >> 3;
    const int h  = tid & 7;
    const float al2 = alpha[(size_t)(base + qi) * 8 + h] * LOG2E_F;   // < 0

    __syncthreads();

    // ---------------- Phase 2: online-softmax lattice attention --------
    float qreg[16];
    {
        const float* qrow = &qkvl[0][qi][h * 20];
        #pragma unroll
        for (int d4 = 0; d4 < 4; ++d4) {
            const float4 t = *(const float4*)(qrow + (d4 << 2));
            qreg[d4 * 4 + 0] = t.x; qreg[d4 * 4 + 1] = t.y;
            qreg[d4 * 4 + 2] = t.z; qreg[d4 * 4 + 3] = t.w;
        }
    }

    float m = -1e30f;
    float den = 0.f;
    float acc[16] = {};
    const float* dp = dist2 + (size_t)(sys * 1024 + qi * 32) * 16;

    #pragma unroll 4
    for (int kj = 0; kj < 32; ++kj, dp += 16) {
        // lattice term: ssum = sum_r exp2(al2*(d2 - mn)), c0 = al2*mn
        const float4 t0 = *(const float4*)(dp + 0);
        const float4 t1 = *(const float4*)(dp + 4);
        const float4 t2 = *(const float4*)(dp + 8);
        const float4 t3 = *(const float4*)(dp + 12);
        const float mn = fminf(
            fminf(fminf(fminf(t0.x, t0.y), fminf(t0.z, t0.w)),
                  fminf(fminf(t1.x, t1.y), fminf(t1.z, t1.w))),
            fminf(fminf(fminf(t2.x, t2.y), fminf(t2.z, t2.w)),
                  fminf(fminf(t3.x, t3.y), fminf(t3.z, t3.w))));
        const float c0 = al2 * mn;   // = max_r(al2*d2), al2 < 0
        float e0 = __builtin_amdgcn_exp2f(fmaf(al2, t0.x, -c0));
        e0 += __builtin_amdgcn_exp2f(fmaf(al2, t0.y, -c0));
        e0 += __builtin_amdgcn_exp2f(fmaf(al2, t0.z, -c0));
        e0 += __builtin_amdgcn_exp2f(fmaf(al2, t0.w, -c0));
        float e1 = __builtin_amdgcn_exp2f(fmaf(al2, t1.x, -c0));
        e1 += __builtin_amdgcn_exp2f(fmaf(al2, t1.y, -c0));
        e1 += __builtin_amdgcn_exp2f(fmaf(al2, t1.z, -c0));
        e1 += __builtin_amdgcn_exp2f(fmaf(al2, t1.w, -c0));
        float e2 = __builtin_amdgcn_exp2f(fmaf(al2, t2.x, -c0));
        e2 += __builtin_amdgcn_exp2f(fmaf(al2, t2.y, -c0));
        e2 += __builtin_amdgcn_exp2f(fmaf(al2, t2.z, -c0));
        e2 += __builtin_amdgcn_exp2f(fmaf(al2, t2.w, -c0));
        float e3 = __builtin_amdgcn_exp2f(fmaf(al2, t3.x, -c0));
        e3 += __builtin_amdgcn_exp2f(fmaf(al2, t3.y, -c0));
        e3 += __builtin_amdgcn_exp2f(fmaf(al2, t3.z, -c0));
        e3 += __builtin_amdgcn_exp2f(fmaf(al2, t3.w, -c0));
        const float ssum = (e0 + e1) + (e2 + e3);   // in [1, 16]

        // q.k dot from LDS
        const float* kr = &qkvl[1][kj][h * 20];
        const float4 k0 = *(const float4*)(kr + 0);
        const float4 k1 = *(const float4*)(kr + 4);
        const float4 k2 = *(const float4*)(kr + 8);
        const float4 k3 = *(const float4*)(kr + 12);
        float p0 = qreg[0] * k0.x, p1 = qreg[1] * k0.y;
        float p2 = qreg[2] * k0.z, p3 = qreg[3] * k0.w;
        p0 = fmaf(qreg[4],  k1.x, p0); p1 = fmaf(qreg[5],  k1.y, p1);
        p2 = fmaf(qreg[6],  k1.z, p2); p3 = fmaf(qreg[7],  k1.w, p3);
        p0 = fmaf(qreg[8],  k2.x, p0); p1 = fmaf(qreg[9],  k2.y, p1);
        p2 = fmaf(qreg[10], k2.z, p2); p3 = fmaf(qreg[11], k2.w, p3);
        p0 = fmaf(qreg[12], k3.x, p0); p1 = fmaf(qreg[13], k3.y, p1);
        p2 = fmaf(qreg[14], k3.z, p2); p3 = fmaf(qreg[15], k3.w, p3);
        const float dot = (p0 + p1) + (p2 + p3);

        const float b = fmaf(dot, LOG2E_F, c0);   // log2-domain score (sans bounded log2(ssum))

        // deferred-max online rescale (THR = 8 in log2 domain)
        if (b - m > 8.0f) {
            const float sc = __builtin_amdgcn_exp2f(m - b);  // 0 on first hit
            den *= sc;
            #pragma unroll
            for (int d = 0; d < 16; ++d) acc[d] *= sc;
            m = b;
        }
        const float p = __builtin_amdgcn_exp2f(b - m) * ssum;  // <= 2^8 * 16
        den += p;

        // PV accumulate
        const float* vr = &qkvl[2][kj][h * 20];
        const float4 v0 = *(const float4*)(vr + 0);
        const float4 v1 = *(const float4*)(vr + 4);
        const float4 v2 = *(const float4*)(vr + 8);
        const float4 v3 = *(const float4*)(vr + 12);
        acc[0]  = fmaf(p, v0.x, acc[0]);  acc[1]  = fmaf(p, v0.y, acc[1]);
        acc[2]  = fmaf(p, v0.z, acc[2]);  acc[3]  = fmaf(p, v0.w, acc[3]);
        acc[4]  = fmaf(p, v1.x, acc[4]);  acc[5]  = fmaf(p, v1.y, acc[5]);
        acc[6]  = fmaf(p, v1.z, acc[6]);  acc[7]  = fmaf(p, v1.w, acc[7]);
        acc[8]  = fmaf(p, v2.x, acc[8]);  acc[9]  = fmaf(p, v2.y, acc[9]);
        acc[10] = fmaf(p, v2.z, acc[10]); acc[11] = fmaf(p, v2.w, acc[11]);
        acc[12] = fmaf(p, v3.x, acc[12]); acc[13] = fmaf(p, v3.y, acc[13]);
        acc[14] = fmaf(p, v3.z, acc[14]); acc[15] = fmaf(p, v3.w, acc[15]);
    }

    // write normalized agg row (bf16) to LDS
    {
        const float inv = 1.0f / den;
        unsigned short* op = &aggb[qi][h * 16];
        uint4 o0, o1;
        o0.x = (unsigned)f2b(acc[0]  * inv) | ((unsigned)f2b(acc[1]  * inv) << 16);
        o0.y = (unsigned)f2b(acc[2]  * inv) | ((unsigned)f2b(acc[3]  * inv) << 16);
        o0.z = (unsigned)f2b(acc[4]  * inv) | ((unsigned)f2b(acc[5]  * inv) << 16);
        o0.w = (unsigned)f2b(acc[6]  * inv) | ((unsigned)f2b(acc[7]  * inv) << 16);
        o1.x = (unsigned)f2b(acc[8]  * inv) | ((unsigned)f2b(acc[9]  * inv) << 16);
        o1.y = (unsigned)f2b(acc[10] * inv) | ((unsigned)f2b(acc[11] * inv) << 16);
        o1.z = (unsigned)f2b(acc[12] * inv) | ((unsigned)f2b(acc[13] * inv) << 16);
        o1.w = (unsigned)f2b(acc[14] * inv) | ((unsigned)f2b(acc[15] * inv) << 16);
        *(uint4*)op       = o0;
        *(uint4*)(op + 8) = o1;
    }

    __syncthreads();

    // ---------------- Phase 3: out-projection -------------------------
    // wave wv owns col-tiles {2wv, 2wv+1} of 8 (128 cols), both row-tiles.
    short8 aA[2][4];
    #pragma unroll
    for (int rt = 0; rt < 2; ++rt)
        #pragma unroll
        for (int ks = 0; ks < 4; ++ks)
            aA[rt][ks] = *(const short8*)(&aggb[rt * 16 + r16][ks * 32 + kg * 8]);

    #pragma unroll
    for (int j = 0; j < 2; ++j) {
        const int ct = wv * 2 + j;            // 0..7
        const int c  = ct * 16 + r16;         // 0..127
        short8 bf[4];
        #pragma unroll
        for (int ks = 0; ks < 4; ++ks)
            bf[ks] = load_frag_f32(Wout + (size_t)c * 128 + ks * 32 + kg * 8);
        const float bias_v = bout[c];
        #pragma unroll
        for (int rt = 0; rt < 2; ++rt) {
            f32x4 oacc = {0.f, 0.f, 0.f, 0.f};
            #pragma unroll
            for (int ks = 0; ks < 4; ++ks)
                oacc = __builtin_amdgcn_mfma_f32_16x16x32_bf16(aA[rt][ks], bf[ks], oacc, 0, 0, 0);
            #pragma unroll
            for (int r = 0; r < 4; ++r) {
                const int row = base + rt * 16 + kg * 4 + r;
                out[(size_t)row * 128 + c] = oacc[r] + bias_v;
            }
        }
    }
}

// =====================================================================
extern "C" void kernel_launch(void* const* d_in, const int* in_sizes, int n_in,
                              void* d_out, int out_size, void* d_ws, size_t ws_size,
                              hipStream_t stream)
{
    const float* x     = (const float*)d_in[0];   // [16384,128]
    const float* Win   = (const float*)d_in[1];   // [384,128]
    const float* bin   = (const float*)d_in[2];   // [384]
    const float* Wout  = (const float*)d_in[3];   // [128,128]
    const float* bout  = (const float*)d_in[4];   // [128]
    const float* alpha = (const float*)d_in[5];   // [16384,8]
    const float* dist2 = (const float*)d_in[6];   // [524288,16]
    // d_in[7] edges, d_in[8] batch: dense block structure, derived analytically

    fused_attn_kernel<<<dim3(512), 256, 0, stream>>>(
        x, Win, bin, Wout, bout, alpha, dist2, (float*)d_out);
}

// Round 5
// 39.885 us; speedup vs baseline: 1.7095x; 1.0914x over previous
//
#include <hip/hip_runtime.h>
#include <hip/hip_bf16.h>

#define LOG2E_F 1.4426950408889634f

typedef __attribute__((ext_vector_type(8))) short short8;
typedef __attribute__((ext_vector_type(4))) float f32x4;

__device__ inline unsigned short f2b(float f) {
    __hip_bfloat16 h = __float2bfloat16(f);   // RNE
    return *reinterpret_cast<unsigned short*>(&h);
}

// load 8 consecutive fp32 and convert to one bf16 MFMA fragment (short8)
__device__ inline short8 load_frag_f32(const float* p) {
    const float4 lo = *(const float4*)p;
    const float4 hi = *(const float4*)(p + 4);
    short8 r;
    r[0] = (short)f2b(lo.x); r[1] = (short)f2b(lo.y);
    r[2] = (short)f2b(lo.z); r[3] = (short)f2b(lo.w);
    r[4] = (short)f2b(hi.x); r[5] = (short)f2b(hi.y);
    r[6] = (short)f2b(hi.z); r[7] = (short)f2b(hi.w);
    return r;
}

// =====================================================================
// Fully fused Crystalformer layer: one block per system (512 blocks,
// 256 threads, 4 waves; 2 blocks/CU, LDS-capped).
//   Phase 1: QKV bf16-MFMA -> LDS qkvl[3][32][164] (fp32)
//   Phase 2: online-softmax lattice attention with double-buffered
//            register prefetch of dist2 (4-kj groups) -> LDS agg (bf16)
//   Phase 3: out-projection bf16-MFMA -> d_out
// __launch_bounds__(256,2): 2 blocks/CU is what LDS allows anyway;
// declaring it unlocks the 256-VGPR budget for the prefetch buffers
// (round-4 compiler allocated only 88 VGPRs -> JIT loads -> 68% stall).
// =====================================================================
__global__ __launch_bounds__(256, 2) void fused_attn_kernel(
    const float* __restrict__ x, const float* __restrict__ Win,
    const float* __restrict__ bin, const float* __restrict__ Wout,
    const float* __restrict__ bout, const float* __restrict__ alpha,
    const float* __restrict__ dist2, float* __restrict__ out)
{
    __shared__ float qkvl[3][32][164];          // 63.0 KB
    __shared__ unsigned short aggb[32][136];    //  8.7 KB

    const int sys  = blockIdx.x;
    const int tid  = threadIdx.x;
    const int lane = tid & 63;
    const int wv   = tid >> 6;
    const int r16  = lane & 15;
    const int kg   = lane >> 4;
    const int base = sys << 5;

    // ---------------- Phase 1: QKV projection into LDS ----------------
    short8 af[2][4];
    #pragma unroll
    for (int rt = 0; rt < 2; ++rt)
        #pragma unroll
        for (int ks = 0; ks < 4; ++ks)
            af[rt][ks] = load_frag_f32(
                x + (size_t)(base + rt * 16 + r16) * 128 + ks * 32 + kg * 8);

    // wave wv owns col-tiles [6wv, 6wv+6) of 24 (384 cols).
    #pragma unroll
    for (int j = 0; j < 6; ++j) {
        const int ct = wv * 6 + j;            // 0..23 (wave-uniform)
        const int c  = ct * 16 + r16;         // global col 0..383
        short8 bf[4];
        #pragma unroll
        for (int ks = 0; ks < 4; ++ks)
            bf[ks] = load_frag_f32(Win + (size_t)c * 128 + ks * 32 + kg * 8);
        const float bias_v = bin[c];
        const int   bufi   = ct >> 3;         // 0=q, 1=k, 2=v
        const int   h      = ct & 7;
        const float scale  = (bufi == 0) ? 0.25f : 1.0f;   // q / sqrt(dh)

        #pragma unroll
        for (int rt = 0; rt < 2; ++rt) {
            f32x4 acc = {0.f, 0.f, 0.f, 0.f};
            #pragma unroll
            for (int ks = 0; ks < 4; ++ks)
                acc = __builtin_amdgcn_mfma_f32_16x16x32_bf16(af[rt][ks], bf[ks], acc, 0, 0, 0);
            // C/D: col = lane&15 (=r16 -> feature), row = kg*4+r (-> atom)
            #pragma unroll
            for (int r = 0; r < 4; ++r) {
                const int atom = rt * 16 + kg * 4 + r;
                qkvl[bufi][atom][h * 20 + r16] = (acc[r] + bias_v) * scale;
            }
        }
    }

    const int qi = tid >> 3;
    const int h  = tid & 7;
    const float al2 = alpha[(size_t)(base + qi) * 8 + h] * LOG2E_F;   // < 0

    __syncthreads();

    // ---------------- Phase 2: online-softmax lattice attention --------
    float qreg[16];
    {
        const float* qrow = &qkvl[0][qi][h * 20];
        #pragma unroll
        for (int d4 = 0; d4 < 4; ++d4) {
            const float4 t = *(const float4*)(qrow + (d4 << 2));
            qreg[d4 * 4 + 0] = t.x; qreg[d4 * 4 + 1] = t.y;
            qreg[d4 * 4 + 2] = t.z; qreg[d4 * 4 + 3] = t.w;
        }
    }

    float m = -1e30f;
    float den = 0.f;
    float acc[16] = {};
    const float* dp = dist2 + (size_t)(sys * 1024 + qi * 32) * 16;

    // double-buffered register prefetch of dist2: 8 groups x 4 kj.
    // Fully unrolled -> all pre[] indices compile-time (no scratch).
    float4 pre[2][16];
    #pragma unroll
    for (int v = 0; v < 16; ++v)
        pre[0][v] = *(const float4*)(dp + v * 4);

    #pragma unroll
    for (int g = 0; g < 8; ++g) {
        const int cur = g & 1;
        const int nxt = cur ^ 1;
        if (g < 7) {
            #pragma unroll
            for (int v = 0; v < 16; ++v)
                pre[nxt][v] = *(const float4*)(dp + (g + 1) * 64 + v * 4);
        }

        #pragma unroll
        for (int i = 0; i < 4; ++i) {
            const int kj = g * 4 + i;
            const float4 t0 = pre[cur][i * 4 + 0];
            const float4 t1 = pre[cur][i * 4 + 1];
            const float4 t2 = pre[cur][i * 4 + 2];
            const float4 t3 = pre[cur][i * 4 + 3];
            const float mn = fminf(
                fminf(fminf(fminf(t0.x, t0.y), fminf(t0.z, t0.w)),
                      fminf(fminf(t1.x, t1.y), fminf(t1.z, t1.w))),
                fminf(fminf(fminf(t2.x, t2.y), fminf(t2.z, t2.w)),
                      fminf(fminf(t3.x, t3.y), fminf(t3.z, t3.w))));
            const float c0 = al2 * mn;   // = max_r(al2*d2), al2 < 0
            float e0 = __builtin_amdgcn_exp2f(fmaf(al2, t0.x, -c0));
            e0 += __builtin_amdgcn_exp2f(fmaf(al2, t0.y, -c0));
            e0 += __builtin_amdgcn_exp2f(fmaf(al2, t0.z, -c0));
            e0 += __builtin_amdgcn_exp2f(fmaf(al2, t0.w, -c0));
            float e1 = __builtin_amdgcn_exp2f(fmaf(al2, t1.x, -c0));
            e1 += __builtin_amdgcn_exp2f(fmaf(al2, t1.y, -c0));
            e1 += __builtin_amdgcn_exp2f(fmaf(al2, t1.z, -c0));
            e1 += __builtin_amdgcn_exp2f(fmaf(al2, t1.w, -c0));
            float e2 = __builtin_amdgcn_exp2f(fmaf(al2, t2.x, -c0));
            e2 += __builtin_amdgcn_exp2f(fmaf(al2, t2.y, -c0));
            e2 += __builtin_amdgcn_exp2f(fmaf(al2, t2.z, -c0));
            e2 += __builtin_amdgcn_exp2f(fmaf(al2, t2.w, -c0));
            float e3 = __builtin_amdgcn_exp2f(fmaf(al2, t3.x, -c0));
            e3 += __builtin_amdgcn_exp2f(fmaf(al2, t3.y, -c0));
            e3 += __builtin_amdgcn_exp2f(fmaf(al2, t3.z, -c0));
            e3 += __builtin_amdgcn_exp2f(fmaf(al2, t3.w, -c0));
            const float ssum = (e0 + e1) + (e2 + e3);   // in [1, 16]

            // q.k dot from LDS
            const float* kr = &qkvl[1][kj][h * 20];
            const float4 k0 = *(const float4*)(kr + 0);
            const float4 k1 = *(const float4*)(kr + 4);
            const float4 k2 = *(const float4*)(kr + 8);
            const float4 k3 = *(const float4*)(kr + 12);
            float p0 = qreg[0] * k0.x, p1 = qreg[1] * k0.y;
            float p2 = qreg[2] * k0.z, p3 = qreg[3] * k0.w;
            p0 = fmaf(qreg[4],  k1.x, p0); p1 = fmaf(qreg[5],  k1.y, p1);
            p2 = fmaf(qreg[6],  k1.z, p2); p3 = fmaf(qreg[7],  k1.w, p3);
            p0 = fmaf(qreg[8],  k2.x, p0); p1 = fmaf(qreg[9],  k2.y, p1);
            p2 = fmaf(qreg[10], k2.z, p2); p3 = fmaf(qreg[11], k2.w, p3);
            p0 = fmaf(qreg[12], k3.x, p0); p1 = fmaf(qreg[13], k3.y, p1);
            p2 = fmaf(qreg[14], k3.z, p2); p3 = fmaf(qreg[15], k3.w, p3);
            const float dot = (p0 + p1) + (p2 + p3);

            const float b = fmaf(dot, LOG2E_F, c0);   // log2-domain score

            // deferred-max online rescale (THR = 8 in log2 domain)
            if (b - m > 8.0f) {
                const float sc = __builtin_amdgcn_exp2f(m - b);  // 0 on first hit
                den *= sc;
                #pragma unroll
                for (int d = 0; d < 16; ++d) acc[d] *= sc;
                m = b;
            }
            const float p = __builtin_amdgcn_exp2f(b - m) * ssum;  // <= 2^8 * 16
            den += p;

            // PV accumulate
            const float* vr = &qkvl[2][kj][h * 20];
            const float4 v0 = *(const float4*)(vr + 0);
            const float4 v1 = *(const float4*)(vr + 4);
            const float4 v2 = *(const float4*)(vr + 8);
            const float4 v3 = *(const float4*)(vr + 12);
            acc[0]  = fmaf(p, v0.x, acc[0]);  acc[1]  = fmaf(p, v0.y, acc[1]);
            acc[2]  = fmaf(p, v0.z, acc[2]);  acc[3]  = fmaf(p, v0.w, acc[3]);
            acc[4]  = fmaf(p, v1.x, acc[4]);  acc[5]  = fmaf(p, v1.y, acc[5]);
            acc[6]  = fmaf(p, v1.z, acc[6]);  acc[7]  = fmaf(p, v1.w, acc[7]);
            acc[8]  = fmaf(p, v2.x, acc[8]);  acc[9]  = fmaf(p, v2.y, acc[9]);
            acc[10] = fmaf(p, v2.z, acc[10]); acc[11] = fmaf(p, v2.w, acc[11]);
            acc[12] = fmaf(p, v3.x, acc[12]); acc[13] = fmaf(p, v3.y, acc[13]);
            acc[14] = fmaf(p, v3.z, acc[14]); acc[15] = fmaf(p, v3.w, acc[15]);
        }
    }

    // write normalized agg row (bf16) to LDS
    {
        const float inv = 1.0f / den;
        unsigned short* op = &aggb[qi][h * 16];
        uint4 o0, o1;
        o0.x = (unsigned)f2b(acc[0]  * inv) | ((unsigned)f2b(acc[1]  * inv) << 16);
        o0.y = (unsigned)f2b(acc[2]  * inv) | ((unsigned)f2b(acc[3]  * inv) << 16);
        o0.z = (unsigned)f2b(acc[4]  * inv) | ((unsigned)f2b(acc[5]  * inv) << 16);
        o0.w = (unsigned)f2b(acc[6]  * inv) | ((unsigned)f2b(acc[7]  * inv) << 16);
        o1.x = (unsigned)f2b(acc[8]  * inv) | ((unsigned)f2b(acc[9]  * inv) << 16);
        o1.y = (unsigned)f2b(acc[10] * inv) | ((unsigned)f2b(acc[11] * inv) << 16);
        o1.z = (unsigned)f2b(acc[12] * inv) | ((unsigned)f2b(acc[13] * inv) << 16);
        o1.w = (unsigned)f2b(acc[14] * inv) | ((unsigned)f2b(acc[15] * inv) << 16);
        *(uint4*)op       = o0;
        *(uint4*)(op + 8) = o1;
    }

    __syncthreads();

    // ---------------- Phase 3: out-projection -------------------------
    short8 aA[2][4];
    #pragma unroll
    for (int rt = 0; rt < 2; ++rt)
        #pragma unroll
        for (int ks = 0; ks < 4; ++ks)
            aA[rt][ks] = *(const short8*)(&aggb[rt * 16 + r16][ks * 32 + kg * 8]);

    #pragma unroll
    for (int j = 0; j < 2; ++j) {
        const int ct = wv * 2 + j;            // 0..7
        const int c  = ct * 16 + r16;         // 0..127
        short8 bf[4];
        #pragma unroll
        for (int ks = 0; ks < 4; ++ks)
            bf[ks] = load_frag_f32(Wout + (size_t)c * 128 + ks * 32 + kg * 8);
        const float bias_v = bout[c];
        #pragma unroll
        for (int rt = 0; rt < 2; ++rt) {
            f32x4 oacc = {0.f, 0.f, 0.f, 0.f};
            #pragma unroll
            for (int ks = 0; ks < 4; ++ks)
                oacc = __builtin_amdgcn_mfma_f32_16x16x32_bf16(aA[rt][ks], bf[ks], oacc, 0, 0, 0);
            #pragma unroll
            for (int r = 0; r < 4; ++r) {
                const int row = base + rt * 16 + kg * 4 + r;
                out[(size_t)row * 128 + c] = oacc[r] + bias_v;
            }
        }
    }
}

// =====================================================================
extern "C" void kernel_launch(void* const* d_in, const int* in_sizes, int n_in,
                              void* d_out, int out_size, void* d_ws, size_t ws_size,
                              hipStream_t stream)
{
    const float* x     = (const float*)d_in[0];   // [16384,128]
    const float* Win   = (const float*)d_in[1];   // [384,128]
    const float* bin   = (const float*)d_in[2];   // [384]
    const float* Wout  = (const float*)d_in[3];   // [128,128]
    const float* bout  = (const float*)d_in[4];   // [128]
    const float* alpha = (const float*)d_in[5];   // [16384,8]
    const float* dist2 = (const float*)d_in[6];   // [524288,16]
    // d_in[7] edges, d_in[8] batch: dense block structure, derived analytically

    fused_attn_kernel<<<dim3(512), 256, 0, stream>>>(
        x, Win, bin, Wout, bout, alpha, dist2, (float*)d_out);
}